// Round 1
// baseline (617.429 us; speedup 1.0000x reference)
//
#include <hip/hip_runtime.h>
#include <hip/hip_bf16.h>

#define Bn 128
#define Tn 512
#define En 100
#define G4 256   // 4*HD
#define Hn 128
#define Kn 12

// Raw barrier: LDS-visibility only (lgkmcnt(0) + s_barrier), leaves vmcnt
// free-running so global prefetch loads survive across barriers (HK pattern).
__device__ __forceinline__ void wg_barrier() {
  asm volatile("s_waitcnt lgkmcnt(0)" ::: "memory");
  __builtin_amdgcn_s_barrier();
  asm volatile("" ::: "memory");
}

// ---------------- K1: embedding gather + input projection ----------------
// xg[n][g] = b_ih[g] + b_hh[g] + sum_e embed[sent[n]][e] * W_ih[g][e]
// block: 256 threads handles 64 rows (n) x 256 gates, gate-chunked by 64.
__global__ __launch_bounds__(256) void proj_kernel(
    const int* __restrict__ sent, const float* __restrict__ embed,
    const float* __restrict__ Wih, const float* __restrict__ bih,
    const float* __restrict__ bhh, float* __restrict__ xg) {
  __shared__ __align__(16) float embT[En * 64];  // [e][r]
  __shared__ __align__(16) float Wt[En * 64];    // [e][g_local]
  __shared__ __align__(16) float bias_s[64];
  const int tid = threadIdx.x;
  const int n0 = blockIdx.x * 64;
  const int r = tid >> 2;          // 0..63 (row for loads / gate for W loads)
  const int eo = (tid & 3) * 25;   // e-range start
  {
    const int row = sent[n0 + r];
    const float* erow = embed + (size_t)row * En;
#pragma unroll
    for (int i = 0; i < 25; ++i) embT[(eo + i) * 64 + r] = erow[eo + i];
  }
  const int rg = tid & 15;   // row group: rows 4*rg..4*rg+3
  const int gg = tid >> 4;   // gate group: gates 4*gg..4*gg+3 (within chunk)
  for (int ch = 0; ch < 4; ++ch) {
    {
      const float* wrow = Wih + (size_t)(ch * 64 + r) * En;
#pragma unroll
      for (int i = 0; i < 25; ++i) Wt[(eo + i) * 64 + r] = wrow[eo + i];
      if (tid < 64) bias_s[tid] = bih[ch * 64 + tid] + bhh[ch * 64 + tid];
    }
    __syncthreads();
    float acc[4][4];
    {
      const float4 bv = *(const float4*)&bias_s[4 * gg];
#pragma unroll
      for (int i = 0; i < 4; ++i) {
        acc[i][0] = bv.x; acc[i][1] = bv.y; acc[i][2] = bv.z; acc[i][3] = bv.w;
      }
    }
#pragma unroll 4
    for (int e = 0; e < En; ++e) {
      const float4 a = *(const float4*)&embT[e * 64 + 4 * rg];
      const float4 w = *(const float4*)&Wt[e * 64 + 4 * gg];
      acc[0][0] = fmaf(a.x, w.x, acc[0][0]); acc[0][1] = fmaf(a.x, w.y, acc[0][1]);
      acc[0][2] = fmaf(a.x, w.z, acc[0][2]); acc[0][3] = fmaf(a.x, w.w, acc[0][3]);
      acc[1][0] = fmaf(a.y, w.x, acc[1][0]); acc[1][1] = fmaf(a.y, w.y, acc[1][1]);
      acc[1][2] = fmaf(a.y, w.z, acc[1][2]); acc[1][3] = fmaf(a.y, w.w, acc[1][3]);
      acc[2][0] = fmaf(a.z, w.x, acc[2][0]); acc[2][1] = fmaf(a.z, w.y, acc[2][1]);
      acc[2][2] = fmaf(a.z, w.z, acc[2][2]); acc[2][3] = fmaf(a.z, w.w, acc[2][3]);
      acc[3][0] = fmaf(a.w, w.x, acc[3][0]); acc[3][1] = fmaf(a.w, w.y, acc[3][1]);
      acc[3][2] = fmaf(a.w, w.z, acc[3][2]); acc[3][3] = fmaf(a.w, w.w, acc[3][3]);
    }
#pragma unroll
    for (int i = 0; i < 4; ++i) {
      *(float4*)&xg[(size_t)(n0 + 4 * rg + i) * G4 + ch * 64 + 4 * gg] =
          make_float4(acc[i][0], acc[i][1], acc[i][2], acc[i][3]);
    }
    __syncthreads();
  }
}

// ---------------- K2: LSTM recurrence ----------------
// One block per (dir, batch). thread g in [0,256) owns gate g; W_hh row in
// registers; h in LDS; c in regs of threads 0..63. 4-deep global prefetch of
// xg survives the raw barriers.
__global__ __launch_bounds__(256) void lstm_kernel(
    const float* __restrict__ xgF, const float* __restrict__ xgB,
    const float* __restrict__ WhhF, const float* __restrict__ WhhB,
    const float* __restrict__ h0, const float* __restrict__ c0,
    float* __restrict__ feats, int dirSel) {
  __shared__ __align__(16) float h_lds[64];
  __shared__ __align__(16) float gates_s[256];
  int d, b;
  if (dirSel < 0) { d = blockIdx.x >> 7; b = blockIdx.x & 127; }
  else            { d = dirSel;          b = blockIdx.x; }
  const int g = threadIdx.x;
  const float* xg = d ? xgB : xgF;
  const float* Whh = d ? WhhB : WhhF;
  float4 wr[16];
  {
    const float4* wp = (const float4*)(Whh + (size_t)g * 64);
#pragma unroll
    for (int kk = 0; kk < 16; ++kk) wr[kk] = wp[kk];
  }
  float c = 0.f;
  if (g < 64) {
    h_lds[g] = h0[(size_t)d * (Bn * 64) + (size_t)b * 64 + g];
    c        = c0[(size_t)d * (Bn * 64) + (size_t)b * 64 + g];
  }
  const int gateGrp = g >> 6;  // 0:i 1:f 2:g 3:o  (wave-uniform)
  const float* xb = xg + (size_t)b * Tn * G4 + g;
  float* fbase = feats + (size_t)b * Tn * Hn + d * 64 + g;  // used only g<64
  const int t0 = d ? (Tn - 1) : 0;
  const int ts = d ? -1 : 1;
  wg_barrier();
  float p0 = xb[(size_t)t0 * G4];
  float p1 = xb[(size_t)(t0 + ts) * G4];
  float p2 = xb[(size_t)(t0 + 2 * ts) * G4];
  float p3 = xb[(size_t)(t0 + 3 * ts) * G4];

#define LSTM_STEP(P, TT) do {                                                  \
    float s0 = 0.f, s1 = 0.f, s2 = 0.f, s3 = 0.f;                              \
    const float4* hp = (const float4*)h_lds;                                   \
    _Pragma("unroll")                                                          \
    for (int kk = 0; kk < 16; ++kk) {                                          \
      const float4 hv = hp[kk]; const float4 wv = wr[kk];                      \
      s0 = fmaf(hv.x, wv.x, s0); s1 = fmaf(hv.y, wv.y, s1);                    \
      s2 = fmaf(hv.z, wv.z, s2); s3 = fmaf(hv.w, wv.w, s3);                    \
    }                                                                          \
    const float accv = (P) + ((s0 + s1) + (s2 + s3));                          \
    const float act = (gateGrp == 2) ? tanhf(accv)                             \
                                     : (1.0f / (1.0f + expf(-accv)));          \
    gates_s[g] = act;                                                          \
    wg_barrier();                                                              \
    if (g < 64) {                                                              \
      const float iv = gates_s[g];       const float fv = gates_s[64 + g];     \
      const float gv = gates_s[128 + g]; const float ov = gates_s[192 + g];    \
      c = fmaf(fv, c, iv * gv);                                                \
      const float hh = ov * tanhf(c);                                          \
      h_lds[g] = hh;                                                           \
      fbase[(size_t)(TT) * Hn] = hh;                                           \
    }                                                                          \
    wg_barrier();                                                              \
  } while (0)

  for (int s = 0; s < Tn; s += 4) {
    const int tA = t0 + s * ts;
    LSTM_STEP(p0, tA);
    if (s + 4 < Tn) p0 = xb[(size_t)(t0 + (s + 4) * ts) * G4];
    LSTM_STEP(p1, tA + ts);
    if (s + 5 < Tn) p1 = xb[(size_t)(t0 + (s + 5) * ts) * G4];
    LSTM_STEP(p2, tA + 2 * ts);
    if (s + 6 < Tn) p2 = xb[(size_t)(t0 + (s + 6) * ts) * G4];
    LSTM_STEP(p3, tA + 3 * ts);
    if (s + 7 < Tn) p3 = xb[(size_t)(t0 + (s + 7) * ts) * G4];
  }
#undef LSTM_STEP
}

// ---------------- K3: emissions = feats @ W_out^T + b_out ----------------
__global__ __launch_bounds__(256) void emis_kernel(
    const float* __restrict__ feats, const float* __restrict__ Wout,
    const float* __restrict__ bout, float* __restrict__ em) {
  __shared__ __align__(16) float Wo[Kn * Hn];
  __shared__ float bo[Kn];
  const int tid = threadIdx.x;
  for (int i = tid; i < Kn * Hn; i += 256) Wo[i] = Wout[i];
  if (tid < Kn) bo[tid] = bout[tid];
  __syncthreads();
  const int n = blockIdx.x * 256 + tid;
  float acc[Kn];
#pragma unroll
  for (int k = 0; k < Kn; ++k) acc[k] = bo[k];
  const float4* fp = (const float4*)(feats + (size_t)n * Hn);
#pragma unroll 4
  for (int d4 = 0; d4 < 32; ++d4) {
    const float4 v = fp[d4];
#pragma unroll
    for (int k = 0; k < Kn; ++k) {
      const float4 w = *(const float4*)&Wo[k * Hn + d4 * 4];
      acc[k] = fmaf(v.x, w.x, acc[k]);
      acc[k] = fmaf(v.y, w.y, acc[k]);
      acc[k] = fmaf(v.z, w.z, acc[k]);
      acc[k] = fmaf(v.w, w.w, acc[k]);
    }
  }
  float* ep = em + (size_t)n * Kn;
#pragma unroll
  for (int k = 0; k < Kn; k += 4)
    *(float4*)&ep[k] = make_float4(acc[k], acc[k + 1], acc[k + 2], acc[k + 3]);
}

// ---------------- K4: Viterbi (one wave per sentence) ----------------
__global__ __launch_bounds__(64) void viterbi_kernel(
    const float* __restrict__ em, const float* __restrict__ trans,
    float* __restrict__ out) {
  __shared__ float em_s[Tn * Kn];
  __shared__ float trans_s[Kn * Kn];
  __shared__ unsigned char bp[(Tn - 1) * Kn];
  __shared__ short path_s[Tn];
  const int tid = threadIdx.x;
  const int b = blockIdx.x;
  const float* eb = em + (size_t)b * Tn * Kn;
  for (int i = tid; i < Tn * Kn; i += 64) em_s[i] = eb[i];
  for (int i = tid; i < Kn * Kn; i += 64) trans_s[i] = trans[i];
  __syncthreads();
  const int lane = (tid < Kn) ? tid : 0;  // lane = to-tag
  float treg[Kn];
#pragma unroll
  for (int f = 0; f < Kn; ++f) treg[f] = trans_s[f * Kn + lane];
  float prev = em_s[lane];                 // trellis[0] = emissions[0]
  for (int t = 1; t < Tn; ++t) {
    float best = __shfl(prev, 0) + treg[0];
    int arg = 0;
#pragma unroll
    for (int f = 1; f < Kn; ++f) {
      const float v = __shfl(prev, f) + treg[f];
      if (v > best) { best = v; arg = f; }   // strict > keeps first argmax
    }
    prev = em_s[t * Kn + lane] + best;
    if (tid < Kn) bp[(t - 1) * Kn + tid] = (unsigned char)arg;
  }
  // final max/argmax over the 12 to-tags (uniform across lanes)
  float bestAll = __shfl(prev, 0);
  int argAll = 0;
#pragma unroll
  for (int f = 1; f < Kn; ++f) {
    const float v = __shfl(prev, f);
    if (v > bestAll) { bestAll = v; argAll = f; }
  }
  __syncthreads();
  if (tid == 0) {
    out[b] = bestAll;
    int cur = argAll;
    for (int i = Tn - 2; i >= 0; --i) {
      path_s[i + 1] = (short)cur;
      cur = bp[i * Kn + cur];
    }
    path_s[0] = (short)cur;
  }
  __syncthreads();
  for (int i = tid; i < Tn; i += 64)
    out[Bn + (size_t)b * Tn + i] = (float)path_s[i];
}

extern "C" void kernel_launch(void* const* d_in, const int* in_sizes, int n_in,
                              void* d_out, int out_size, void* d_ws, size_t ws_size,
                              hipStream_t stream) {
  const int*   sent  = (const int*)d_in[0];
  const float* embed = (const float*)d_in[1];
  const float* Wih_f = (const float*)d_in[2];
  const float* Whh_f = (const float*)d_in[3];
  const float* bih_f = (const float*)d_in[4];
  const float* bhh_f = (const float*)d_in[5];
  const float* Wih_b = (const float*)d_in[6];
  const float* Whh_b = (const float*)d_in[7];
  const float* bih_b = (const float*)d_in[8];
  const float* bhh_b = (const float*)d_in[9];
  const float* Wout  = (const float*)d_in[10];
  const float* bout  = (const float*)d_in[11];
  const float* trans = (const float*)d_in[12];
  const float* h0    = (const float*)d_in[13];
  const float* c0    = (const float*)d_in[14];
  float* out = (float*)d_out;  // [128 scores][128*512 path tags as float]

  char* ws = (char*)d_ws;
  const size_t xgBytes   = (size_t)Bn * Tn * G4 * sizeof(float);  // 64 MiB
  const size_t featBytes = (size_t)Bn * Tn * Hn * sizeof(float);  // 32 MiB
  const size_t emBytes   = (size_t)Bn * Tn * Kn * sizeof(float);  //  3 MiB
  const int projGrid = (Bn * Tn) / 64;  // 1024

  if (ws_size >= 2 * xgBytes + featBytes + emBytes) {
    // Parallel layout: both directions' recurrences run in one launch.
    float* xgF   = (float*)ws;
    float* xgB   = (float*)(ws + xgBytes);
    float* feats = (float*)(ws + 2 * xgBytes);
    float* emis  = (float*)(ws + 2 * xgBytes + featBytes);
    proj_kernel<<<projGrid, 256, 0, stream>>>(sent, embed, Wih_f, bih_f, bhh_f, xgF);
    proj_kernel<<<projGrid, 256, 0, stream>>>(sent, embed, Wih_b, bih_b, bhh_b, xgB);
    lstm_kernel<<<256, 256, 0, stream>>>(xgF, xgB, Whh_f, Whh_b, h0, c0, feats, -1);
    emis_kernel<<<256, 256, 0, stream>>>(feats, Wout, bout, emis);
    viterbi_kernel<<<128, 64, 0, stream>>>(emis, trans, out);
  } else {
    // Sequential fallback: reuse one xg buffer for both directions.
    float* xgS   = (float*)ws;
    float* feats = (float*)(ws + xgBytes);
    float* emis  = (float*)(ws + xgBytes + featBytes);
    proj_kernel<<<projGrid, 256, 0, stream>>>(sent, embed, Wih_f, bih_f, bhh_f, xgS);
    lstm_kernel<<<128, 256, 0, stream>>>(xgS, xgS, Whh_f, Whh_f, h0, c0, feats, 0);
    proj_kernel<<<projGrid, 256, 0, stream>>>(sent, embed, Wih_b, bih_b, bhh_b, xgS);
    lstm_kernel<<<128, 256, 0, stream>>>(xgS, xgS, Whh_b, Whh_b, h0, c0, feats, 1);
    emis_kernel<<<256, 256, 0, stream>>>(feats, Wout, bout, emis);
    viterbi_kernel<<<128, 64, 0, stream>>>(emis, trans, out);
  }
}

// Round 2
// 485.030 us; speedup vs baseline: 1.2730x; 1.2730x over previous
//
#include <hip/hip_runtime.h>
#include <hip/hip_bf16.h>

#define Bn 128
#define Tn 512
#define En 100
#define G4 256   // 4*HD
#define Hn 128
#define Kn 12

// Raw barrier: lgkmcnt(0) ensures all in-flight LDS reads have landed in
// VGPRs before the barrier (cross-wave WAR safety), s_barrier without the
// compiler's vmcnt(0) drain so global prefetch loads stay in flight.
__device__ __forceinline__ void wg_barrier() {
  asm volatile("s_waitcnt lgkmcnt(0)" ::: "memory");
  __builtin_amdgcn_s_barrier();
  asm volatile("" ::: "memory");
}

// Hardware transcendentals via inline asm (v_exp_f32 is 2^x per ISA).
__device__ __forceinline__ float exp2_hw(float x) {
  float r; asm("v_exp_f32 %0, %1" : "=v"(r) : "v"(x)); return r;
}
__device__ __forceinline__ float rcp_hw(float x) {
  float r; asm("v_rcp_f32 %0, %1" : "=v"(r) : "v"(x)); return r;
}
__device__ __forceinline__ float fast_sigm(float x) {
  // 1/(1+e^-x); branchless, safe for |x| up to ~85
  return rcp_hw(1.0f + exp2_hw(x * -1.4426950408889634f));
}
__device__ __forceinline__ float fast_tanh(float x) {
  // 1 - 2/(e^{2x}+1); e^{2x}->inf gives rcp(inf)=0 -> 1; ->0 gives -1
  return 1.0f - 2.0f * rcp_hw(1.0f + exp2_hw(x * 2.8853900817779268f));
}

// ---------------- K1: embedding gather + input projection ----------------
__global__ __launch_bounds__(256) void proj_kernel(
    const int* __restrict__ sent, const float* __restrict__ embed,
    const float* __restrict__ Wih, const float* __restrict__ bih,
    const float* __restrict__ bhh, float* __restrict__ xg) {
  __shared__ __align__(16) float embT[En * 64];  // [e][r]
  __shared__ __align__(16) float Wt[En * 64];    // [e][g_local]
  __shared__ __align__(16) float bias_s[64];
  const int tid = threadIdx.x;
  const int n0 = blockIdx.x * 64;
  const int r = tid >> 2;
  const int eo = (tid & 3) * 25;
  {
    const int row = sent[n0 + r];
    const float* erow = embed + (size_t)row * En;
#pragma unroll
    for (int i = 0; i < 25; ++i) embT[(eo + i) * 64 + r] = erow[eo + i];
  }
  const int rg = tid & 15;
  const int gg = tid >> 4;
  for (int ch = 0; ch < 4; ++ch) {
    {
      const float* wrow = Wih + (size_t)(ch * 64 + r) * En;
#pragma unroll
      for (int i = 0; i < 25; ++i) Wt[(eo + i) * 64 + r] = wrow[eo + i];
      if (tid < 64) bias_s[tid] = bih[ch * 64 + tid] + bhh[ch * 64 + tid];
    }
    __syncthreads();
    float acc[4][4];
    {
      const float4 bv = *(const float4*)&bias_s[4 * gg];
#pragma unroll
      for (int i = 0; i < 4; ++i) {
        acc[i][0] = bv.x; acc[i][1] = bv.y; acc[i][2] = bv.z; acc[i][3] = bv.w;
      }
    }
#pragma unroll 4
    for (int e = 0; e < En; ++e) {
      const float4 a = *(const float4*)&embT[e * 64 + 4 * rg];
      const float4 w = *(const float4*)&Wt[e * 64 + 4 * gg];
      acc[0][0] = fmaf(a.x, w.x, acc[0][0]); acc[0][1] = fmaf(a.x, w.y, acc[0][1]);
      acc[0][2] = fmaf(a.x, w.z, acc[0][2]); acc[0][3] = fmaf(a.x, w.w, acc[0][3]);
      acc[1][0] = fmaf(a.y, w.x, acc[1][0]); acc[1][1] = fmaf(a.y, w.y, acc[1][1]);
      acc[1][2] = fmaf(a.y, w.z, acc[1][2]); acc[1][3] = fmaf(a.y, w.w, acc[1][3]);
      acc[2][0] = fmaf(a.z, w.x, acc[2][0]); acc[2][1] = fmaf(a.z, w.y, acc[2][1]);
      acc[2][2] = fmaf(a.z, w.z, acc[2][2]); acc[2][3] = fmaf(a.z, w.w, acc[2][3]);
      acc[3][0] = fmaf(a.w, w.x, acc[3][0]); acc[3][1] = fmaf(a.w, w.y, acc[3][1]);
      acc[3][2] = fmaf(a.w, w.z, acc[3][2]); acc[3][3] = fmaf(a.w, w.w, acc[3][3]);
    }
#pragma unroll
    for (int i = 0; i < 4; ++i) {
      *(float4*)&xg[(size_t)(n0 + 4 * rg + i) * G4 + ch * 64 + 4 * gg] =
          make_float4(acc[i][0], acc[i][1], acc[i][2], acc[i][3]);
    }
    __syncthreads();
  }
}

// ---------------- K2: LSTM recurrence (restructured) ----------------
// One block per (dir,batch), 4 waves. Wave w owns gate-type w for all 64
// units (lane j = unit j). Per step: ONE barrier (gates exchange through a
// double-buffered LDS slab); every wave redundantly computes the c/h update
// so h lives in each wave's registers + its own private h_lds copy (no
// cross-wave h dependency, no second barrier).
__global__ __launch_bounds__(256) void lstm_kernel(
    const float* __restrict__ xgF, const float* __restrict__ xgB,
    const float* __restrict__ WhhF, const float* __restrict__ WhhB,
    const float* __restrict__ h0, const float* __restrict__ c0,
    float* __restrict__ feats, int dirSel) {
  __shared__ __align__(16) float h_lds[4][64];     // per-wave private copies
  __shared__ __align__(16) float gates_s[2][256];  // dbuf, layout [j*4+w]
  int d, b;
  if (dirSel < 0) { d = blockIdx.x >> 7; b = blockIdx.x & 127; }
  else            { d = dirSel;          b = blockIdx.x; }
  const int g = threadIdx.x;
  const int j = g & 63;
  const int w = g >> 6;
  const int w_u = __builtin_amdgcn_readfirstlane(w);  // SGPR -> scalar branches
  const float* xg = d ? xgB : xgF;
  const float* Whh = d ? WhhB : WhhF;
  float4 wr[16];
  {
    const float4* wp = (const float4*)(Whh + (size_t)g * 64);
#pragma unroll
    for (int kk = 0; kk < 16; ++kk) wr[kk] = wp[kk];
  }
  float c = c0[(size_t)d * (Bn * 64) + (size_t)b * 64 + j];
  h_lds[w][j] = h0[(size_t)d * (Bn * 64) + (size_t)b * 64 + j];
  const float* xb = xg + (size_t)b * Tn * G4 + g;
  float* fbase = feats + (size_t)b * Tn * Hn + d * 64 + j;  // wave0 stores
  const int t0 = d ? (Tn - 1) : 0;
  const int ts = d ? -1 : 1;
  float p0 = xb[(size_t)t0 * G4];
  float p1 = xb[(size_t)(t0 + ts) * G4];
  float p2 = xb[(size_t)(t0 + 2 * ts) * G4];
  float p3 = xb[(size_t)(t0 + 3 * ts) * G4];

#define LSTM_STEP(P, TT, PAR) do {                                             \
    float s0 = 0.f, s1 = 0.f, s2 = 0.f, s3 = 0.f;                              \
    const float4* hp = (const float4*)h_lds[w];                                \
    _Pragma("unroll")                                                          \
    for (int kk = 0; kk < 16; ++kk) {                                          \
      const float4 hv = hp[kk]; const float4 wv = wr[kk];                      \
      s0 = fmaf(hv.x, wv.x, s0); s1 = fmaf(hv.y, wv.y, s1);                    \
      s2 = fmaf(hv.z, wv.z, s2); s3 = fmaf(hv.w, wv.w, s3);                    \
    }                                                                          \
    const float accv = (P) + ((s0 + s1) + (s2 + s3));                          \
    float act;                                                                 \
    if (w_u == 2) act = fast_tanh(accv); else act = fast_sigm(accv);           \
    gates_s[PAR][4 * j + w] = act;                                             \
    wg_barrier();                                                              \
    const float4 gv = *(const float4*)&gates_s[PAR][4 * j];                    \
    c = fmaf(gv.y, c, gv.x * gv.z);                                            \
    const float hh = gv.w * fast_tanh(c);                                      \
    h_lds[w][j] = hh;                                                          \
    if (w_u == 0) fbase[(size_t)(TT) * Hn] = hh;                               \
  } while (0)

  for (int s = 0; s < Tn; s += 4) {
    const int tA = t0 + s * ts;
    LSTM_STEP(p0, tA, 0);
    if (s + 4 < Tn) p0 = xb[(size_t)(t0 + (s + 4) * ts) * G4];
    LSTM_STEP(p1, tA + ts, 1);
    if (s + 5 < Tn) p1 = xb[(size_t)(t0 + (s + 5) * ts) * G4];
    LSTM_STEP(p2, tA + 2 * ts, 0);
    if (s + 6 < Tn) p2 = xb[(size_t)(t0 + (s + 6) * ts) * G4];
    LSTM_STEP(p3, tA + 3 * ts, 1);
    if (s + 7 < Tn) p3 = xb[(size_t)(t0 + (s + 7) * ts) * G4];
  }
#undef LSTM_STEP
}

// ---------------- K3: emissions = feats @ W_out^T + b_out ----------------
__global__ __launch_bounds__(256) void emis_kernel(
    const float* __restrict__ feats, const float* __restrict__ Wout,
    const float* __restrict__ bout, float* __restrict__ em) {
  __shared__ __align__(16) float Wo[Kn * Hn];
  __shared__ float bo[Kn];
  const int tid = threadIdx.x;
  for (int i = tid; i < Kn * Hn; i += 256) Wo[i] = Wout[i];
  if (tid < Kn) bo[tid] = bout[tid];
  __syncthreads();
  const int n = blockIdx.x * 256 + tid;
  float acc[Kn];
#pragma unroll
  for (int k = 0; k < Kn; ++k) acc[k] = bo[k];
  const float4* fp = (const float4*)(feats + (size_t)n * Hn);
#pragma unroll 4
  for (int d4 = 0; d4 < 32; ++d4) {
    const float4 v = fp[d4];
#pragma unroll
    for (int k = 0; k < Kn; ++k) {
      const float4 w = *(const float4*)&Wo[k * Hn + d4 * 4];
      acc[k] = fmaf(v.x, w.x, acc[k]);
      acc[k] = fmaf(v.y, w.y, acc[k]);
      acc[k] = fmaf(v.z, w.z, acc[k]);
      acc[k] = fmaf(v.w, w.w, acc[k]);
    }
  }
  float* ep = em + (size_t)n * Kn;
#pragma unroll
  for (int k = 0; k < Kn; k += 4)
    *(float4*)&ep[k] = make_float4(acc[k], acc[k + 1], acc[k + 2], acc[k + 3]);
}

// ---------------- K4: Viterbi (one wave per sentence) ----------------
#define AMAX(v, a, v2, a2) { if ((v2) > (v)) { (v) = (v2); (a) = (a2); } }

__global__ __launch_bounds__(64) void viterbi_kernel(
    const float* __restrict__ em, const float* __restrict__ trans,
    float* __restrict__ out) {
  __shared__ __align__(16) float em_s[Tn * Kn];
  __shared__ float trans_s[Kn * Kn];
  __shared__ unsigned char bp[(Tn - 1) * Kn];
  __shared__ short path_s[Tn];
  const int tid = threadIdx.x;
  const int b = blockIdx.x;
  {
    const float4* ebv = (const float4*)(em + (size_t)b * Tn * Kn);
    float4* emv = (float4*)em_s;
    for (int i = tid; i < (Tn * Kn) / 4; i += 64) emv[i] = ebv[i];
  }
  for (int i = tid; i < Kn * Kn; i += 64) trans_s[i] = trans[i];
  __syncthreads();
  const int lane = (tid < Kn) ? tid : 0;  // lane = to-tag
  float treg[Kn];
#pragma unroll
  for (int f = 0; f < Kn; ++f) treg[f] = trans_s[f * Kn + lane];
  float prev = em_s[lane];
  for (int t = 1; t < Tn; ++t) {
    float cv[Kn];
#pragma unroll
    for (int f = 0; f < Kn; ++f) cv[f] = __shfl(prev, f) + treg[f];
    // depth-4 argmax tree, first-index-on-tie (strict > keeps left/lower)
    float m0 = cv[0], m1 = cv[2], m2 = cv[4], m3 = cv[6], m4 = cv[8], m5 = cv[10];
    int a0 = 0, a1 = 2, a2 = 4, a3 = 6, a4 = 8, a5 = 10;
    AMAX(m0, a0, cv[1], 1);  AMAX(m1, a1, cv[3], 3);
    AMAX(m2, a2, cv[5], 5);  AMAX(m3, a3, cv[7], 7);
    AMAX(m4, a4, cv[9], 9);  AMAX(m5, a5, cv[11], 11);
    AMAX(m0, a0, m1, a1); AMAX(m2, a2, m3, a3); AMAX(m4, a4, m5, a5);
    AMAX(m0, a0, m2, a2); AMAX(m0, a0, m4, a4);
    prev = em_s[t * Kn + lane] + m0;
    if (tid < Kn) bp[(t - 1) * Kn + tid] = (unsigned char)a0;
  }
  // final max/argmax over the 12 to-tags
  float fv[Kn];
#pragma unroll
  for (int f = 0; f < Kn; ++f) fv[f] = __shfl(prev, f);
  float m0 = fv[0], m1 = fv[2], m2 = fv[4], m3 = fv[6], m4 = fv[8], m5 = fv[10];
  int a0 = 0, a1 = 2, a2 = 4, a3 = 6, a4 = 8, a5 = 10;
  AMAX(m0, a0, fv[1], 1);  AMAX(m1, a1, fv[3], 3);
  AMAX(m2, a2, fv[5], 5);  AMAX(m3, a3, fv[7], 7);
  AMAX(m4, a4, fv[9], 9);  AMAX(m5, a5, fv[11], 11);
  AMAX(m0, a0, m1, a1); AMAX(m2, a2, m3, a3); AMAX(m4, a4, m5, a5);
  AMAX(m0, a0, m2, a2); AMAX(m0, a0, m4, a4);
  __syncthreads();
  if (tid == 0) {
    out[b] = m0;
    int cur = a0;
    for (int i = Tn - 2; i >= 0; --i) {
      path_s[i + 1] = (short)cur;
      cur = bp[i * Kn + cur];
    }
    path_s[0] = (short)cur;
  }
  __syncthreads();
  for (int i = tid; i < Tn; i += 64)
    out[Bn + (size_t)b * Tn + i] = (float)path_s[i];
}

extern "C" void kernel_launch(void* const* d_in, const int* in_sizes, int n_in,
                              void* d_out, int out_size, void* d_ws, size_t ws_size,
                              hipStream_t stream) {
  const int*   sent  = (const int*)d_in[0];
  const float* embed = (const float*)d_in[1];
  const float* Wih_f = (const float*)d_in[2];
  const float* Whh_f = (const float*)d_in[3];
  const float* bih_f = (const float*)d_in[4];
  const float* bhh_f = (const float*)d_in[5];
  const float* Wih_b = (const float*)d_in[6];
  const float* Whh_b = (const float*)d_in[7];
  const float* bih_b = (const float*)d_in[8];
  const float* bhh_b = (const float*)d_in[9];
  const float* Wout  = (const float*)d_in[10];
  const float* bout  = (const float*)d_in[11];
  const float* trans = (const float*)d_in[12];
  const float* h0    = (const float*)d_in[13];
  const float* c0    = (const float*)d_in[14];
  float* out = (float*)d_out;

  char* ws = (char*)d_ws;
  const size_t xgBytes   = (size_t)Bn * Tn * G4 * sizeof(float);  // 64 MiB
  const size_t featBytes = (size_t)Bn * Tn * Hn * sizeof(float);  // 32 MiB
  const size_t emBytes   = (size_t)Bn * Tn * Kn * sizeof(float);  //  3 MiB
  const int projGrid = (Bn * Tn) / 64;  // 1024

  if (ws_size >= 2 * xgBytes + featBytes + emBytes) {
    float* xgF   = (float*)ws;
    float* xgB   = (float*)(ws + xgBytes);
    float* feats = (float*)(ws + 2 * xgBytes);
    float* emis  = (float*)(ws + 2 * xgBytes + featBytes);
    proj_kernel<<<projGrid, 256, 0, stream>>>(sent, embed, Wih_f, bih_f, bhh_f, xgF);
    proj_kernel<<<projGrid, 256, 0, stream>>>(sent, embed, Wih_b, bih_b, bhh_b, xgB);
    lstm_kernel<<<256, 256, 0, stream>>>(xgF, xgB, Whh_f, Whh_b, h0, c0, feats, -1);
    emis_kernel<<<256, 256, 0, stream>>>(feats, Wout, bout, emis);
    viterbi_kernel<<<128, 64, 0, stream>>>(emis, trans, out);
  } else {
    float* xgS   = (float*)ws;
    float* feats = (float*)(ws + xgBytes);
    float* emis  = (float*)(ws + xgBytes + featBytes);
    proj_kernel<<<projGrid, 256, 0, stream>>>(sent, embed, Wih_f, bih_f, bhh_f, xgS);
    lstm_kernel<<<128, 256, 0, stream>>>(xgS, xgS, Whh_f, Whh_f, h0, c0, feats, 0);
    proj_kernel<<<projGrid, 256, 0, stream>>>(sent, embed, Wih_b, bih_b, bhh_b, xgS);
    lstm_kernel<<<128, 256, 0, stream>>>(xgS, xgS, Whh_b, Whh_b, h0, c0, feats, 1);
    emis_kernel<<<256, 256, 0, stream>>>(feats, Wout, bout, emis);
    viterbi_kernel<<<128, 64, 0, stream>>>(emis, trans, out);
  }
}

// Round 3
// 454.683 us; speedup vs baseline: 1.3579x; 1.0667x over previous
//
#include <hip/hip_runtime.h>
#include <hip/hip_bf16.h>

#define Bn 128
#define Tn 512
#define En 100
#define G4 256   // 4*HD
#define Hn 128
#define Kn 12

// Raw barrier: lgkmcnt(0) ensures in-flight LDS ops landed (cross-wave WAR
// safety), s_barrier without the compiler's vmcnt(0) drain so global
// prefetch loads stay in flight across it.
__device__ __forceinline__ void wg_barrier() {
  asm volatile("s_waitcnt lgkmcnt(0)" ::: "memory");
  __builtin_amdgcn_s_barrier();
  asm volatile("" ::: "memory");
}

__device__ __forceinline__ float exp2_hw(float x) {
  float r; asm("v_exp_f32 %0, %1" : "=v"(r) : "v"(x)); return r;
}
__device__ __forceinline__ float rcp_hw(float x) {
  float r; asm("v_rcp_f32 %0, %1" : "=v"(r) : "v"(x)); return r;
}
__device__ __forceinline__ float fast_sigm(float x) {
  return rcp_hw(1.0f + exp2_hw(x * -1.4426950408889634f));
}
__device__ __forceinline__ float fast_tanh(float x) {
  return 1.0f - 2.0f * rcp_hw(1.0f + exp2_hw(x * 2.8853900817779268f));
}

// ---------------- K1: embedding gather + input projection ----------------
__global__ __launch_bounds__(256) void proj_kernel(
    const int* __restrict__ sent, const float* __restrict__ embed,
    const float* __restrict__ Wih, const float* __restrict__ bih,
    const float* __restrict__ bhh, float* __restrict__ xg) {
  __shared__ __align__(16) float embT[En * 64];  // [e][r]
  __shared__ __align__(16) float Wt[En * 64];    // [e][g_local]
  __shared__ __align__(16) float bias_s[64];
  const int tid = threadIdx.x;
  const int n0 = blockIdx.x * 64;
  const int r = tid >> 2;
  const int eo = (tid & 3) * 25;
  {
    const int row = sent[n0 + r];
    const float* erow = embed + (size_t)row * En;
#pragma unroll
    for (int i = 0; i < 25; ++i) embT[(eo + i) * 64 + r] = erow[eo + i];
  }
  const int rg = tid & 15;
  const int gg = tid >> 4;
  for (int ch = 0; ch < 4; ++ch) {
    {
      const float* wrow = Wih + (size_t)(ch * 64 + r) * En;
#pragma unroll
      for (int i = 0; i < 25; ++i) Wt[(eo + i) * 64 + r] = wrow[eo + i];
      if (tid < 64) bias_s[tid] = bih[ch * 64 + tid] + bhh[ch * 64 + tid];
    }
    __syncthreads();
    float acc[4][4];
    {
      const float4 bv = *(const float4*)&bias_s[4 * gg];
#pragma unroll
      for (int i = 0; i < 4; ++i) {
        acc[i][0] = bv.x; acc[i][1] = bv.y; acc[i][2] = bv.z; acc[i][3] = bv.w;
      }
    }
#pragma unroll 4
    for (int e = 0; e < En; ++e) {
      const float4 a = *(const float4*)&embT[e * 64 + 4 * rg];
      const float4 w = *(const float4*)&Wt[e * 64 + 4 * gg];
      acc[0][0] = fmaf(a.x, w.x, acc[0][0]); acc[0][1] = fmaf(a.x, w.y, acc[0][1]);
      acc[0][2] = fmaf(a.x, w.z, acc[0][2]); acc[0][3] = fmaf(a.x, w.w, acc[0][3]);
      acc[1][0] = fmaf(a.y, w.x, acc[1][0]); acc[1][1] = fmaf(a.y, w.y, acc[1][1]);
      acc[1][2] = fmaf(a.y, w.z, acc[1][2]); acc[1][3] = fmaf(a.y, w.w, acc[1][3]);
      acc[2][0] = fmaf(a.z, w.x, acc[2][0]); acc[2][1] = fmaf(a.z, w.y, acc[2][1]);
      acc[2][2] = fmaf(a.z, w.z, acc[2][2]); acc[2][3] = fmaf(a.z, w.w, acc[2][3]);
      acc[3][0] = fmaf(a.w, w.x, acc[3][0]); acc[3][1] = fmaf(a.w, w.y, acc[3][1]);
      acc[3][2] = fmaf(a.w, w.z, acc[3][2]); acc[3][3] = fmaf(a.w, w.w, acc[3][3]);
    }
#pragma unroll
    for (int i = 0; i < 4; ++i) {
      *(float4*)&xg[(size_t)(n0 + 4 * rg + i) * G4 + ch * 64 + 4 * gg] =
          make_float4(acc[i][0], acc[i][1], acc[i][2], acc[i][3]);
    }
    __syncthreads();
  }
}

// ---------------- K2: LSTM recurrence (K-split, 8 waves/pair) ----------------
// One block (512 threads) per (dir,b) pair -> 8 waves/CU = 2/SIMD on all 256
// CUs. Thread = (gate g = tid>>1, half = tid&1): 32-long half-dot, halves
// combined with shfl_xor(1). Gate exchange: double-buffered gates_s[buf][g]
// (conflict-free both sides), ONE barrier/step. h is per-wave-private in LDS
// (own-wave write->read, lgkmcnt-ordered, no barrier dependency). c held
// redundantly per wave (lane l owns unit l).
__global__ __launch_bounds__(512) void lstm_kernel(
    const float* __restrict__ xgF, const float* __restrict__ xgB,
    const float* __restrict__ WhhF, const float* __restrict__ WhhB,
    const float* __restrict__ h0, const float* __restrict__ c0,
    float* __restrict__ feats, int dirSel) {
  __shared__ __align__(16) float h_lds[8][64];     // per-wave private copies
  __shared__ __align__(16) float gates_s[2][256];  // [buf][g], g = type*64+unit
  int d, b;
  if (dirSel < 0) { d = blockIdx.x >> 7; b = blockIdx.x & 127; }
  else            { d = dirSel;          b = blockIdx.x; }
  const int tid = threadIdx.x;
  const int g = tid >> 1;        // gate row 0..255
  const int half = tid & 1;      // K half
  const int l = tid & 63;        // lane
  const int w = tid >> 6;        // wave 0..7
  const int w_u = __builtin_amdgcn_readfirstlane(w);
  const int isTanhW = (w_u >> 1) == 2;   // gate type g>>6 == 2 (PyTorch i,f,g,o)
  const float* xg = d ? xgB : xgF;
  const float* Whh = d ? WhhB : WhhF;
  float4 wr[8];
  {
    const float4* wp = (const float4*)(Whh + (size_t)g * 64 + 32 * half);
#pragma unroll
    for (int kk = 0; kk < 8; ++kk) wr[kk] = wp[kk];
  }
  float c = c0[(size_t)d * (Bn * 64) + (size_t)b * 64 + l];
  h_lds[w][l] = h0[(size_t)d * (Bn * 64) + (size_t)b * 64 + l];
  const float* xb = xg + (size_t)b * Tn * G4 + g;
  float* fbase = feats + (size_t)b * Tn * Hn + d * 64 + l;  // wave 0 stores
  const int t0 = d ? (Tn - 1) : 0;
  const int ts = d ? -1 : 1;
  float p0 = 0.f, p1 = 0.f, p2 = 0.f, p3 = 0.f;
  if (half == 0) {
    p0 = xb[(size_t)t0 * G4];
    p1 = xb[(size_t)(t0 + ts) * G4];
    p2 = xb[(size_t)(t0 + 2 * ts) * G4];
    p3 = xb[(size_t)(t0 + 3 * ts) * G4];
  }

#define LSTM_STEP(P, TT, PAR) do {                                             \
    float s0 = 0.f, s1 = 0.f, s2 = 0.f, s3 = 0.f;                              \
    const float4* hp = (const float4*)(&h_lds[w][32 * half]);                  \
    _Pragma("unroll")                                                          \
    for (int kk = 0; kk < 8; ++kk) {                                           \
      const float4 hv = hp[kk]; const float4 wv = wr[kk];                      \
      s0 = fmaf(hv.x, wv.x, s0); s1 = fmaf(hv.y, wv.y, s1);                    \
      s2 = fmaf(hv.z, wv.z, s2); s3 = fmaf(hv.w, wv.w, s3);                    \
    }                                                                          \
    const float smine = (s0 + s1) + (s2 + s3);                                 \
    const float stot = smine + __shfl_xor(smine, 1);                           \
    if (half == 0) {                                                           \
      const float accv = (P) + stot;                                           \
      const float act = isTanhW ? fast_tanh(accv) : fast_sigm(accv);           \
      gates_s[PAR][g] = act;                                                   \
    }                                                                          \
    wg_barrier();                                                              \
    const float g0 = gates_s[PAR][l];                                          \
    const float g1 = gates_s[PAR][64 + l];                                     \
    const float g2 = gates_s[PAR][128 + l];                                    \
    const float g3 = gates_s[PAR][192 + l];                                    \
    c = fmaf(g1, c, g0 * g2);                                                  \
    const float hh = g3 * fast_tanh(c);                                        \
    h_lds[w][l] = hh;                                                          \
    if (w_u == 0) fbase[(size_t)(TT) * Hn] = hh;                               \
  } while (0)

  for (int s = 0; s < Tn; s += 4) {
    const int tA = t0 + s * ts;
    LSTM_STEP(p0, tA, 0);
    if (half == 0 && s + 4 < Tn) p0 = xb[(size_t)(t0 + (s + 4) * ts) * G4];
    LSTM_STEP(p1, tA + ts, 1);
    if (half == 0 && s + 5 < Tn) p1 = xb[(size_t)(t0 + (s + 5) * ts) * G4];
    LSTM_STEP(p2, tA + 2 * ts, 0);
    if (half == 0 && s + 6 < Tn) p2 = xb[(size_t)(t0 + (s + 6) * ts) * G4];
    LSTM_STEP(p3, tA + 3 * ts, 1);
    if (half == 0 && s + 7 < Tn) p3 = xb[(size_t)(t0 + (s + 7) * ts) * G4];
  }
#undef LSTM_STEP
}

// ---------------- K3: emissions = feats @ W_out^T + b_out ----------------
__global__ __launch_bounds__(256) void emis_kernel(
    const float* __restrict__ feats, const float* __restrict__ Wout,
    const float* __restrict__ bout, float* __restrict__ em) {
  __shared__ __align__(16) float Wo[Kn * Hn];
  __shared__ float bo[Kn];
  const int tid = threadIdx.x;
  for (int i = tid; i < Kn * Hn; i += 256) Wo[i] = Wout[i];
  if (tid < Kn) bo[tid] = bout[tid];
  __syncthreads();
  const int n = blockIdx.x * 256 + tid;
  float acc[Kn];
#pragma unroll
  for (int k = 0; k < Kn; ++k) acc[k] = bo[k];
  const float4* fp = (const float4*)(feats + (size_t)n * Hn);
#pragma unroll 4
  for (int d4 = 0; d4 < 32; ++d4) {
    const float4 v = fp[d4];
#pragma unroll
    for (int k = 0; k < Kn; ++k) {
      const float4 w = *(const float4*)&Wo[k * Hn + d4 * 4];
      acc[k] = fmaf(v.x, w.x, acc[k]);
      acc[k] = fmaf(v.y, w.y, acc[k]);
      acc[k] = fmaf(v.z, w.z, acc[k]);
      acc[k] = fmaf(v.w, w.w, acc[k]);
    }
  }
  float* ep = em + (size_t)n * Kn;
#pragma unroll
  for (int k = 0; k < Kn; k += 4)
    *(float4*)&ep[k] = make_float4(acc[k], acc[k + 1], acc[k + 2], acc[k + 3]);
}

// ---------------- K4: Viterbi (one wave per sentence) ----------------
#define AMAX(v, a, v2, a2) { if ((v2) > (v)) { (v) = (v2); (a) = (a2); } }

__global__ __launch_bounds__(64) void viterbi_kernel(
    const float* __restrict__ em, const float* __restrict__ trans,
    float* __restrict__ out) {
  __shared__ __align__(16) float em_s[Tn * Kn];
  __shared__ float trans_s[Kn * Kn];
  __shared__ unsigned char bp[(Tn - 1) * Kn];
  __shared__ short path_s[Tn];
  const int tid = threadIdx.x;
  const int b = blockIdx.x;
  {
    const float4* ebv = (const float4*)(em + (size_t)b * Tn * Kn);
    float4* emv = (float4*)em_s;
    for (int i = tid; i < (Tn * Kn) / 4; i += 64) emv[i] = ebv[i];
  }
  for (int i = tid; i < Kn * Kn; i += 64) trans_s[i] = trans[i];
  __syncthreads();
  const int lane = (tid < Kn) ? tid : 0;  // lane = to-tag
  float treg[Kn];
#pragma unroll
  for (int f = 0; f < Kn; ++f) treg[f] = trans_s[f * Kn + lane];
  float prev = em_s[lane];
  for (int t = 1; t < Tn; ++t) {
    float cv[Kn];
#pragma unroll
    for (int f = 0; f < Kn; ++f) cv[f] = __shfl(prev, f) + treg[f];
    float m0 = cv[0], m1 = cv[2], m2 = cv[4], m3 = cv[6], m4 = cv[8], m5 = cv[10];
    int a0 = 0, a1 = 2, a2 = 4, a3 = 6, a4 = 8, a5 = 10;
    AMAX(m0, a0, cv[1], 1);  AMAX(m1, a1, cv[3], 3);
    AMAX(m2, a2, cv[5], 5);  AMAX(m3, a3, cv[7], 7);
    AMAX(m4, a4, cv[9], 9);  AMAX(m5, a5, cv[11], 11);
    AMAX(m0, a0, m1, a1); AMAX(m2, a2, m3, a3); AMAX(m4, a4, m5, a5);
    AMAX(m0, a0, m2, a2); AMAX(m0, a0, m4, a4);
    prev = em_s[t * Kn + lane] + m0;
    if (tid < Kn) bp[(t - 1) * Kn + tid] = (unsigned char)a0;
  }
  float fv[Kn];
#pragma unroll
  for (int f = 0; f < Kn; ++f) fv[f] = __shfl(prev, f);
  float m0 = fv[0], m1 = fv[2], m2 = fv[4], m3 = fv[6], m4 = fv[8], m5 = fv[10];
  int a0 = 0, a1 = 2, a2 = 4, a3 = 6, a4 = 8, a5 = 10;
  AMAX(m0, a0, fv[1], 1);  AMAX(m1, a1, fv[3], 3);
  AMAX(m2, a2, fv[5], 5);  AMAX(m3, a3, fv[7], 7);
  AMAX(m4, a4, fv[11], 11);
  AMAX(m5, a5, fv[11], 11);
  // (redo cleanly to keep first-index tie semantics)
  m0 = fv[0]; m1 = fv[2]; m2 = fv[4]; m3 = fv[6]; m4 = fv[8]; m5 = fv[10];
  a0 = 0; a1 = 2; a2 = 4; a3 = 6; a4 = 8; a5 = 10;
  AMAX(m0, a0, fv[1], 1);  AMAX(m1, a1, fv[3], 3);
  AMAX(m2, a2, fv[5], 5);  AMAX(m3, a3, fv[7], 7);
  AMAX(m4, a4, fv[9], 9);  AMAX(m5, a5, fv[11], 11);
  AMAX(m0, a0, m1, a1); AMAX(m2, a2, m3, a3); AMAX(m4, a4, m5, a5);
  AMAX(m0, a0, m2, a2); AMAX(m0, a0, m4, a4);
  __syncthreads();
  if (tid == 0) {
    out[b] = m0;
    int cur = a0;
    for (int i = Tn - 2; i >= 0; --i) {
      path_s[i + 1] = (short)cur;
      cur = bp[i * Kn + cur];
    }
    path_s[0] = (short)cur;
  }
  __syncthreads();
  for (int i = tid; i < Tn; i += 64)
    out[Bn + (size_t)b * Tn + i] = (float)path_s[i];
}

extern "C" void kernel_launch(void* const* d_in, const int* in_sizes, int n_in,
                              void* d_out, int out_size, void* d_ws, size_t ws_size,
                              hipStream_t stream) {
  const int*   sent  = (const int*)d_in[0];
  const float* embed = (const float*)d_in[1];
  const float* Wih_f = (const float*)d_in[2];
  const float* Whh_f = (const float*)d_in[3];
  const float* bih_f = (const float*)d_in[4];
  const float* bhh_f = (const float*)d_in[5];
  const float* Wih_b = (const float*)d_in[6];
  const float* Whh_b = (const float*)d_in[7];
  const float* bih_b = (const float*)d_in[8];
  const float* bhh_b = (const float*)d_in[9];
  const float* Wout  = (const float*)d_in[10];
  const float* bout  = (const float*)d_in[11];
  const float* trans = (const float*)d_in[12];
  const float* h0    = (const float*)d_in[13];
  const float* c0    = (const float*)d_in[14];
  float* out = (float*)d_out;

  char* ws = (char*)d_ws;
  const size_t xgBytes   = (size_t)Bn * Tn * G4 * sizeof(float);  // 64 MiB
  const size_t featBytes = (size_t)Bn * Tn * Hn * sizeof(float);  // 32 MiB
  const size_t emBytes   = (size_t)Bn * Tn * Kn * sizeof(float);  //  3 MiB
  const int projGrid = (Bn * Tn) / 64;  // 1024

  if (ws_size >= 2 * xgBytes + featBytes + emBytes) {
    float* xgF   = (float*)ws;
    float* xgB   = (float*)(ws + xgBytes);
    float* feats = (float*)(ws + 2 * xgBytes);
    float* emis  = (float*)(ws + 2 * xgBytes + featBytes);
    proj_kernel<<<projGrid, 256, 0, stream>>>(sent, embed, Wih_f, bih_f, bhh_f, xgF);
    proj_kernel<<<projGrid, 256, 0, stream>>>(sent, embed, Wih_b, bih_b, bhh_b, xgB);
    lstm_kernel<<<256, 512, 0, stream>>>(xgF, xgB, Whh_f, Whh_b, h0, c0, feats, -1);
    emis_kernel<<<256, 256, 0, stream>>>(feats, Wout, bout, emis);
    viterbi_kernel<<<128, 64, 0, stream>>>(emis, trans, out);
  } else {
    float* xgS   = (float*)ws;
    float* feats = (float*)(ws + xgBytes);
    float* emis  = (float*)(ws + xgBytes + featBytes);
    proj_kernel<<<projGrid, 256, 0, stream>>>(sent, embed, Wih_f, bih_f, bhh_f, xgS);
    lstm_kernel<<<128, 512, 0, stream>>>(xgS, xgS, Whh_f, Whh_f, h0, c0, feats, 0);
    proj_kernel<<<projGrid, 256, 0, stream>>>(sent, embed, Wih_b, bih_b, bhh_b, xgS);
    lstm_kernel<<<128, 512, 0, stream>>>(xgS, xgS, Whh_b, Whh_b, h0, c0, feats, 1);
    emis_kernel<<<256, 256, 0, stream>>>(feats, Wout, bout, emis);
    viterbi_kernel<<<128, 64, 0, stream>>>(emis, trans, out);
  }
}